// Round 7
// baseline (139.833 us; speedup 1.0000x reference)
//
#include <hip/hip_runtime.h>
#include <hip/hip_cooperative_groups.h>

namespace cg = cooperative_groups;

// Greedy NMS, M=16384 pts, radius 2.0, torch PairwiseDistance eps=1e-6.
// Output INT32: mask[16384] as 0/1, then count[1].
//
// Round 7: single cooperative kernel (zero | bin | edge-scan | solve) with
// grid.sync() between phases — eliminates 3 inter-kernel graph-node gaps,
// which the r5/r6 A-B deltas identified as the dominant residual (~20 us).
// Blocks 1..N-1 write trivially-kept outputs while block 0 solves.
// Round-6 four-kernel path kept as fallback if cooperative launch fails.

#define M_PTS    16384
#define RADIUS   2.0f
#define EPS_D    1e-6f
#define GRID_N   25        // 4 m cells over 100 m scene
#define NCELLS   (GRID_N * GRID_N * GRID_N)
#define CELL_CAP 12
#define K_NBR    12
#define NBLK     256
#define NTHR     512
#define EPT      10
#define ACT_PAD  (EPT * NTHR)   // 5120; E[active]~3932 -> 21 sigma headroom
#define NTASK    (M_PTS * 27)

// ws layout (bytes):
//   [0,       262144) float4 pts[16384]
//   [262144,  324644) int    cell_cnt[15625]   --+ contiguous, zeroed as one
//   [324644,  390180) int    cnt[16384]        --+ 32009-int region
//   [393216,  768216) ushort cell_list[15625*12]
//   [770048, 1163264) ushort nbr[16384*12]

__device__ __forceinline__ int cell_of(float v) {
  int c = (int)(v * 0.25f);
  return c < 0 ? 0 : (c > GRID_N - 1 ? GRID_N - 1 : c);
}

__device__ __forceinline__ bool edge_test(float4 pi, float4 pj, int j, int i) {
  // j earlier in argsort(-score, stable) AND dist <= radius (exact ref math)
  bool earlier = (pj.w > pi.w) || ((pj.w == pi.w) && (j < i));
  if (!earlier) return false;
  float ddx = __fadd_rn(__fsub_rn(pi.x, pj.x), EPS_D);
  float ddy = __fadd_rn(__fsub_rn(pi.y, pj.y), EPS_D);
  float ddz = __fadd_rn(__fsub_rn(pi.z, pj.z), EPS_D);
  float d2 = __fadd_rn(__fadd_rn(__fmul_rn(ddx, ddx), __fmul_rn(ddy, ddy)),
                       __fmul_rn(ddz, ddz));
  return !(__fsqrt_rn(d2) > RADIUS);
}

__global__ __launch_bounds__(NTHR) void nms_fused(
    const float* __restrict__ nodes, const float* __restrict__ score,
    float4* __restrict__ pts, int* __restrict__ cell_cnt,
    unsigned short* __restrict__ cell_list, int* __restrict__ cnt,
    unsigned short* __restrict__ nbr, int* __restrict__ out, int out_size) {
  __shared__ unsigned char mask_[M_PTS];   // 16 KB (block 0 solve only)
  __shared__ unsigned int act[ACT_PAD];    // 20 KB: k | (c<<16)
  __shared__ int act_n, total;
  volatile unsigned char* mask = mask_;

  cg::grid_group gg = cg::this_grid();
  const int tid = threadIdx.x;
  const int g   = blockIdx.x * NTHR + tid;
  const int gsz = NBLK * NTHR;             // 131072

  // ---- P0: zero cell_cnt + cnt (contiguous 32009-int region) ----
  for (int i = g; i < NCELLS + M_PTS; i += gsz) cell_cnt[i] = 0;
  gg.sync();

  // ---- P1: bin points into 4 m cells ----
  if (g < M_PTS) {
    float4 p;
    p.x = nodes[3 * g + 0];
    p.y = nodes[3 * g + 1];
    p.z = nodes[3 * g + 2];
    p.w = score[g];
    pts[g] = p;
    int cid = (cell_of(p.x) * GRID_N + cell_of(p.y)) * GRID_N + cell_of(p.z);
    int pos = atomicAdd(&cell_cnt[cid], 1);
    if (pos < CELL_CAP) cell_list[cid * CELL_CAP + pos] = (unsigned short)g;
  }
  gg.sync();

  // ---- P2: one task per (point i, one of 27 candidate cells) ----
  for (int t = g; t < NTASK; t += gsz) {
    int i = t / 27;
    int d = t - i * 27;
    const float4 pi = pts[i];
    int cx = cell_of(pi.x) + (d / 9) - 1;
    int cy = cell_of(pi.y) + ((d / 3) % 3) - 1;
    int cz = cell_of(pi.z) + (d % 3) - 1;
    if (cx < 0 || cx >= GRID_N || cy < 0 || cy >= GRID_N ||
        cz < 0 || cz >= GRID_N) continue;
    int cid = (cx * GRID_N + cy) * GRID_N + cz;
    int m = cell_cnt[cid];
    if (m > CELL_CAP) m = CELL_CAP;
    for (int s = 0; s < m; ++s) {
      int j = cell_list[cid * CELL_CAP + s];
      if (edge_test(pi, pts[j], j, i)) {
        int pos = atomicAdd(&cnt[i], 1);
        if (pos < K_NBR) nbr[i * K_NBR + pos] = (unsigned short)j;
      }
    }
  }
  gg.sync();

  // ---- P3a: blocks 1..N-1 write trivially-kept outputs and exit ----
  if (blockIdx.x != 0) {
    int g2 = (blockIdx.x - 1) * NTHR + tid;
    int gsz2 = (NBLK - 1) * NTHR;
    for (int k = g2; k < M_PTS; k += gsz2)
      if (cnt[k] == 0) out[k] = 1;
    return;
  }

  // ---- P3b: block 0 solves the fixpoint (512 threads) ----
  const int lane = tid & 63;
  if (tid == 0) { act_n = 0; total = 0; }
  for (int a = tid; a < ACT_PAD; a += NTHR) act[a] = 0u;  // c=0 sentinels
  __syncthreads();

  for (int k = tid; k < M_PTS; k += NTHR) {   // 32 full steps
    mask_[k] = 1;
    int c = cnt[k];
    if (c > K_NBR) c = K_NBR;
    unsigned long long b = __ballot(c > 0);
    int wcnt = __popcll(b);
    int wbase = 0;
    if (lane == 0 && wcnt) wbase = atomicAdd(&act_n, wcnt);
    wbase = __shfl(wbase, 0, 64);
    if (c > 0) {
      int pos = wbase + __popcll(b & ((1ull << lane) - 1ull));
      if (pos < ACT_PAD) act[pos] = (unsigned)k | ((unsigned)c << 16);
    }
  }
  __syncthreads();
  const int na = act_n;
  const bool ok = (na <= ACT_PAD);

  unsigned ae[EPT];
  unsigned short r0[EPT], r1[EPT], r2[EPT];
#pragma unroll
  for (int e = 0; e < EPT; ++e) {
    unsigned v = act[tid + e * NTHR];
    ae[e] = v;
    int k = (int)(v & 0xFFFFu);
    int c = (int)(v >> 16);
    const unsigned short* row = nbr + (size_t)k * K_NBR;
    r0[e] = (c > 0) ? row[0] : (unsigned short)0;
    r1[e] = (c > 1) ? row[1] : (unsigned short)0;
    r2[e] = (c > 2) ? row[2] : (unsigned short)0;
  }
  __syncthreads();

  if (ok) {
    for (int it = 0; it < 96; ++it) {
      int any = 0;
      int m0[EPT];
#pragma unroll
      for (int e = 0; e < EPT; ++e) m0[e] = (int)mask[r0[e]];  // batched
#pragma unroll
      for (int e = 0; e < EPT; ++e) {
        unsigned v = ae[e];
        int c = (int)(v >> 16);
        if (!c) continue;
        int k = (int)(v & 0xFFFFu);
        int kp = m0[e] ^ 1;
        if (c > 1) kp &= (int)mask[r1[e]] ^ 1;
        if (c > 2) kp &= (int)mask[r2[e]] ^ 1;
        if (c > 3) {
          const unsigned short* row = nbr + (size_t)k * K_NBR;
          for (int t = 3; t < c; ++t) kp &= (int)mask[row[t]] ^ 1;
        }
        if (kp != (int)mask[k]) { mask[k] = (unsigned char)kp; any = 1; }
      }
      if (__syncthreads_count(any) == 0) break;
    }
    // epilogue: write active outputs + count (inactive written by other blocks)
    int ks = 0;
    for (int a = tid; a < na; a += NTHR) {
      int k = (int)(act[a] & 0xFFFFu);
      int m = (int)mask_[k];
      out[k] = m;
      ks += m;
    }
#pragma unroll
    for (int off = 32; off > 0; off >>= 1) ks += __shfl_down(ks, off, 64);
    if (lane == 0) atomicAdd(&total, ks);
    __syncthreads();
    if (tid == 0) out[out_size - 1] = (M_PTS - na) + total;
  } else {
    // overflow fallback (statistically never): barriered global sweeps
    __shared__ int changed;
    for (int it = 0; it < 512; ++it) {
      if (tid == 0) changed = 0;
      __syncthreads();
      int any = 0;
      for (int k = tid; k < M_PTS; k += NTHR) {
        int c = cnt[k]; if (c > K_NBR) c = K_NBR;
        if (!c) continue;
        int kp = 1;
        for (int t = 0; t < c; ++t) kp &= (int)mask[nbr[k * K_NBR + t]] ^ 1;
        if (kp != (int)mask[k]) { mask_[k] = (unsigned char)kp; any = 1; }
      }
      if (any) changed = 1;
      __syncthreads();
      if (!changed) break;
    }
    __syncthreads();
    int ks = 0;
    for (int k = tid; k < M_PTS; k += NTHR) {
      int m = (int)mask_[k];
      out[k] = m;
      ks += m;
    }
#pragma unroll
    for (int off = 32; off > 0; off >>= 1) ks += __shfl_down(ks, off, 64);
    if (lane == 0) atomicAdd(&total, ks);
    __syncthreads();
    if (tid == 0) out[out_size - 1] = total;
  }
}

// ---------------- fallback path (round-6 kernels, proven) ----------------

__global__ __launch_bounds__(256) void zero_kernel(int4* __restrict__ p) {
  int i = blockIdx.x * 256 + threadIdx.x;
  if (i < 8003) p[i] = make_int4(0, 0, 0, 0);
}

__global__ __launch_bounds__(256) void grid_build(
    const float* __restrict__ nodes, const float* __restrict__ score,
    float4* __restrict__ pts, int* __restrict__ cell_cnt,
    unsigned short* __restrict__ cell_list) {
  int i = blockIdx.x * 256 + threadIdx.x;
  if (i >= M_PTS) return;
  float4 p;
  p.x = nodes[3 * i + 0];
  p.y = nodes[3 * i + 1];
  p.z = nodes[3 * i + 2];
  p.w = score[i];
  pts[i] = p;
  int cid = (cell_of(p.x) * GRID_N + cell_of(p.y)) * GRID_N + cell_of(p.z);
  int pos = atomicAdd(&cell_cnt[cid], 1);
  if (pos < CELL_CAP) cell_list[cid * CELL_CAP + pos] = (unsigned short)i;
}

__global__ __launch_bounds__(256) void nbr_scan(
    const float4* __restrict__ pts, const int* __restrict__ cell_cnt,
    const unsigned short* __restrict__ cell_list,
    int* __restrict__ cnt, unsigned short* __restrict__ nbr) {
  int t = blockIdx.x * 256 + threadIdx.x;
  int i = t / 27;
  int d = t - i * 27;
  if (i >= M_PTS) return;
  const float4 pi = pts[i];
  int cx = cell_of(pi.x) + (d / 9) - 1;
  int cy = cell_of(pi.y) + ((d / 3) % 3) - 1;
  int cz = cell_of(pi.z) + (d % 3) - 1;
  if (cx < 0 || cx >= GRID_N || cy < 0 || cy >= GRID_N ||
      cz < 0 || cz >= GRID_N) return;
  int cid = (cx * GRID_N + cy) * GRID_N + cz;
  int m = cell_cnt[cid];
  if (m > CELL_CAP) m = CELL_CAP;
  for (int s = 0; s < m; ++s) {
    int j = cell_list[cid * CELL_CAP + s];
    if (edge_test(pi, pts[j], j, i)) {
      int pos = atomicAdd(&cnt[i], 1);
      if (pos < K_NBR) nbr[i * K_NBR + pos] = (unsigned short)j;
    }
  }
}

__global__ __launch_bounds__(1024) void solve_kernel(
    const int* __restrict__ cnt, const unsigned short* __restrict__ nbr,
    int* __restrict__ out, int out_size) {
  __shared__ unsigned char mask_[M_PTS];
  __shared__ unsigned int act[ACT_PAD];
  __shared__ int act_n, total;
  volatile unsigned char* mask = mask_;

  const int tid = threadIdx.x;
  const int lane = tid & 63;
  if (tid == 0) { act_n = 0; total = 0; }
  for (int a = tid; a < ACT_PAD; a += 1024) act[a] = 0u;
  __syncthreads();

  for (int k = tid; k < M_PTS; k += 1024) {
    mask_[k] = 1;
    int c = cnt[k];
    if (c > K_NBR) c = K_NBR;
    unsigned long long b = __ballot(c > 0);
    int wcnt = __popcll(b);
    int wbase = 0;
    if (lane == 0 && wcnt) wbase = atomicAdd(&act_n, wcnt);
    wbase = __shfl(wbase, 0, 64);
    if (c > 0) {
      int pos = wbase + __popcll(b & ((1ull << lane) - 1ull));
      if (pos < ACT_PAD) act[pos] = (unsigned)k | ((unsigned)c << 16);
    }
  }
  __syncthreads();
  const int na = act_n;
  const bool ok = (na <= ACT_PAD);

  const int FEPT = 5;
  unsigned ae[FEPT];
  unsigned short r0[FEPT], r1[FEPT], r2[FEPT];
#pragma unroll
  for (int e = 0; e < FEPT; ++e) {
    unsigned v = act[tid + e * 1024];
    ae[e] = v;
    int k = (int)(v & 0xFFFFu);
    int c = (int)(v >> 16);
    const unsigned short* row = nbr + (size_t)k * K_NBR;
    r0[e] = (c > 0) ? row[0] : (unsigned short)0;
    r1[e] = (c > 1) ? row[1] : (unsigned short)0;
    r2[e] = (c > 2) ? row[2] : (unsigned short)0;
  }
  __syncthreads();

  if (ok) {
    for (int it = 0; it < 96; ++it) {
      int any = 0;
      int m0[FEPT];
#pragma unroll
      for (int e = 0; e < FEPT; ++e) m0[e] = (int)mask[r0[e]];
#pragma unroll
      for (int e = 0; e < FEPT; ++e) {
        unsigned v = ae[e];
        int c = (int)(v >> 16);
        if (!c) continue;
        int k = (int)(v & 0xFFFFu);
        int kp = m0[e] ^ 1;
        if (c > 1) kp &= (int)mask[r1[e]] ^ 1;
        if (c > 2) kp &= (int)mask[r2[e]] ^ 1;
        if (c > 3) {
          const unsigned short* row = nbr + (size_t)k * K_NBR;
          for (int t = 3; t < c; ++t) kp &= (int)mask[row[t]] ^ 1;
        }
        if (kp != (int)mask[k]) { mask[k] = (unsigned char)kp; any = 1; }
      }
      if (__syncthreads_count(any) == 0) break;
    }
  } else {
    __shared__ int changed;
    for (int it = 0; it < 512; ++it) {
      if (tid == 0) changed = 0;
      __syncthreads();
      int any = 0;
      for (int k = tid; k < M_PTS; k += 1024) {
        int c = cnt[k]; if (c > K_NBR) c = K_NBR;
        if (!c) continue;
        int kp = 1;
        for (int t = 0; t < c; ++t) kp &= (int)mask[nbr[k * K_NBR + t]] ^ 1;
        if (kp != (int)mask[k]) { mask_[k] = (unsigned char)kp; any = 1; }
      }
      if (any) changed = 1;
      __syncthreads();
      if (!changed) break;
    }
  }
  __syncthreads();

  int ks = 0;
  for (int k = tid; k < M_PTS; k += 1024) {
    int m = (int)mask_[k];
    out[k] = m;
    ks += m;
  }
#pragma unroll
  for (int off = 32; off > 0; off >>= 1) ks += __shfl_down(ks, off, 64);
  if (lane == 0) atomicAdd(&total, ks);
  __syncthreads();
  if (tid == 0) out[out_size - 1] = total;
}

extern "C" void kernel_launch(void* const* d_in, const int* in_sizes, int n_in,
                              void* d_out, int out_size, void* d_ws, size_t ws_size,
                              hipStream_t stream) {
  const float* nodes = (const float*)d_in[0];
  const float* score = (const float*)d_in[1];
  int* out = (int*)d_out;

  char* ws = (char*)d_ws;
  float4* pts = (float4*)ws;
  int* cell_cnt = (int*)(ws + 262144);
  int* cnt = (int*)(ws + 324644);
  unsigned short* cell_list = (unsigned short*)(ws + 393216);
  unsigned short* nbr = (unsigned short*)(ws + 770048);

  void* args[] = {(void*)&nodes, (void*)&score, (void*)&pts, (void*)&cell_cnt,
                  (void*)&cell_list, (void*)&cnt, (void*)&nbr, (void*)&out,
                  (void*)&out_size};
  hipError_t err = hipLaunchCooperativeKernel(
      (const void*)nms_fused, dim3(NBLK), dim3(NTHR), args, 0, stream);
  if (err != hipSuccess) {
    // proven 4-kernel path
    zero_kernel<<<32, 256, 0, stream>>>((int4*)(ws + 262144));
    grid_build<<<64, 256, 0, stream>>>(nodes, score, pts, cell_cnt, cell_list);
    nbr_scan<<<1728, 256, 0, stream>>>(pts, cell_cnt, cell_list, cnt, nbr);
    solve_kernel<<<1, 1024, 0, stream>>>(cnt, nbr, out, out_size);
  }
}

// Round 8
// 89.229 us; speedup vs baseline: 1.5671x; 1.5671x over previous
//
#include <hip/hip_runtime.h>

// Greedy NMS, M=16384 pts, radius 2.0, torch PairwiseDistance eps=1e-6.
// Output INT32: mask[16384] as 0/1, then count[1].
//
// Round 8: two dispatches, zero grid.syncs (r7 showed grid.sync ~30us each).
//  K1 build1b  (1 block): zero cell table in LDS, bin points, flush, zero flag.
//  K2 scan_solve (128 blocks): wave-cooperative edge scan (2 pts/wave, shfl
//    segmented-scan packing, no atomics, no cnt zeroing); last-finishing block
//    (device-scope atomic + threadfence, schedule-independent) runs the
//    register-staged fixpoint solve and writes mask + count.

#define M_PTS    16384
#define RADIUS   2.0f
#define EPS_D    1e-6f
#define GRID_N   25        // 4 m cells over 100 m scene
#define NCELLS   (GRID_N * GRID_N * GRID_N)
#define CELL_CAP 12
#define K_NBR    12
#define EPT      5
#define ACT_PAD  (EPT * 1024)   // 5120; E[active]~3932 -> 21 sigma headroom
#define NBLK2    128
#define NTHR2    1024
#define WTASKS   (M_PTS / 2)            // 8192 wave-tasks (2 points per wave)
#define GWAVES   (NBLK2 * NTHR2 / 64)   // 2048 waves -> 4 tasks per wave

// ws layout (bytes):
//   [0,       262144) float4 pts[16384]
//   [262144,  324644) int    cell_cnt[15625]
//   [324644,  324648) int    done
//   [327680,  393216) int    cnt[16384]
//   [393216,  768216) ushort cell_list[15625*12]
//   [770048, 1163264) ushort nbr[16384*12]

__device__ __forceinline__ int cell_of(float v) {
  int c = (int)(v * 0.25f);
  return c < 0 ? 0 : (c > GRID_N - 1 ? GRID_N - 1 : c);
}

__device__ __forceinline__ bool edge_test(float4 pi, float4 pj, int j, int i) {
  // j earlier in argsort(-score, stable) AND dist <= radius (exact ref math)
  bool earlier = (pj.w > pi.w) || ((pj.w == pi.w) && (j < i));
  if (!earlier) return false;
  float ddx = __fadd_rn(__fsub_rn(pi.x, pj.x), EPS_D);
  float ddy = __fadd_rn(__fsub_rn(pi.y, pj.y), EPS_D);
  float ddz = __fadd_rn(__fsub_rn(pi.z, pj.z), EPS_D);
  float d2 = __fadd_rn(__fadd_rn(__fmul_rn(ddx, ddx), __fmul_rn(ddy, ddy)),
                       __fmul_rn(ddz, ddz));
  return !(__fsqrt_rn(d2) > RADIUS);
}

// ---- K1: single block. LDS cell table: zero -> bin -> flush. ----
__global__ __launch_bounds__(1024) void build1b(
    const float* __restrict__ nodes, const float* __restrict__ score,
    float4* __restrict__ pts, int* __restrict__ cell_cnt,
    unsigned short* __restrict__ cell_list, int* __restrict__ done) {
  __shared__ int ccnt[NCELLS];   // 62.5 KB
  const int tid = threadIdx.x;
  for (int c = tid; c < NCELLS; c += 1024) ccnt[c] = 0;
  __syncthreads();
  for (int i = tid; i < M_PTS; i += 1024) {
    float4 p;
    p.x = nodes[3 * i + 0];
    p.y = nodes[3 * i + 1];
    p.z = nodes[3 * i + 2];
    p.w = score[i];
    pts[i] = p;
    int cid = (cell_of(p.x) * GRID_N + cell_of(p.y)) * GRID_N + cell_of(p.z);
    int pos = atomicAdd(&ccnt[cid], 1);
    if (pos < CELL_CAP) cell_list[cid * CELL_CAP + pos] = (unsigned short)i;
  }
  __syncthreads();
  for (int c = tid; c < NCELLS; c += 1024) {
    int v = ccnt[c];
    cell_cnt[c] = v > CELL_CAP ? CELL_CAP : v;
  }
  if (tid == 0) *done = 0;
}

// ---- K2: wave-coop scan; last-finishing block solves. ----
__global__ __launch_bounds__(NTHR2) void scan_solve(
    const float4* __restrict__ pts, const int* __restrict__ cell_cnt,
    const unsigned short* __restrict__ cell_list,
    int* __restrict__ cnt, unsigned short* __restrict__ nbr,
    int* __restrict__ done, int* __restrict__ out, int out_size) {
  __shared__ unsigned char mask_[M_PTS];   // 16 KB (solve only)
  __shared__ unsigned int act[ACT_PAD];    // 20 KB: k | (c<<16)
  __shared__ int act_n, total, islast;
  volatile unsigned char* mask = mask_;

  const int tid  = threadIdx.x;
  const int lane = tid & 63;
  const int d    = lane & 31;     // cell slot within point: 0..26 active
  const int half = lane >> 5;     // which of the wave's 2 points
  const int gwave = (blockIdx.x * NTHR2 + tid) >> 6;

  // ---- scan: 2 points per wave, one candidate cell per lane ----
  for (int wt = gwave; wt < WTASKS; wt += GWAVES) {
    int i = wt * 2 + half;
    float4 pi = pts[i];
    int n = 0, cid = 0, m = 0;
    if (d < 27) {
      int cx = cell_of(pi.x) + d / 9 - 1;
      int cy = cell_of(pi.y) + (d / 3) % 3 - 1;
      int cz = cell_of(pi.z) + d % 3 - 1;
      if (cx >= 0 && cx < GRID_N && cy >= 0 && cy < GRID_N &&
          cz >= 0 && cz < GRID_N) {
        cid = (cx * GRID_N + cy) * GRID_N + cz;
        m = cell_cnt[cid];
        for (int s = 0; s < m; ++s) {
          int j = cell_list[cid * CELL_CAP + s];
          if (edge_test(pi, pts[j], j, i)) ++n;
        }
      }
    }
    // segmented inclusive scan over the 32-lane half -> packing offsets
    int x = n;
#pragma unroll
    for (int off = 1; off < 32; off <<= 1) {
      int y = __shfl_up(x, off, 32);
      if (d >= off) x += y;
    }
    int excl = x - n;
    int tot = __shfl(x, 31, 32);   // lanes 27..31 contribute 0
    if (n > 0) {                   // second pass (L1-hot) writes edges
      int pos = excl;
      for (int s = 0; s < m && pos < K_NBR; ++s) {
        int j = cell_list[cid * CELL_CAP + s];
        if (edge_test(pi, pts[j], j, i)) {
          nbr[i * K_NBR + pos] = (unsigned short)j;
          ++pos;
        }
      }
    }
    if (d == 0) cnt[i] = tot > K_NBR ? K_NBR : tot;
  }

  // ---- last-finishing block proceeds to solve (schedule-independent) ----
  __syncthreads();
  __threadfence();                         // release our cnt/nbr writes
  if (tid == 0) {
    int old = atomicAdd(done, 1);          // device-scope RMW
    islast = (old == NBLK2 - 1);
  }
  __syncthreads();
  if (!islast) return;
  __threadfence();                         // acquire other blocks' writes

  // ---- solve: ballot-compacted active list, EPT=5 register rows ----
  const int lane64 = lane;
  if (tid == 0) { act_n = 0; total = 0; }
  for (int a = tid; a < ACT_PAD; a += NTHR2) act[a] = 0u;  // c=0 sentinels
  __syncthreads();

  for (int k = tid; k < M_PTS; k += NTHR2) {   // 16 full steps
    mask_[k] = 1;
    int c = cnt[k];
    if (c > K_NBR) c = K_NBR;
    unsigned long long b = __ballot(c > 0);
    int wcnt = __popcll(b);
    int wbase = 0;
    if (lane64 == 0 && wcnt) wbase = atomicAdd(&act_n, wcnt);
    wbase = __shfl(wbase, 0, 64);
    if (c > 0) {
      int pos = wbase + __popcll(b & ((1ull << lane64) - 1ull));
      if (pos < ACT_PAD) act[pos] = (unsigned)k | ((unsigned)c << 16);
    }
  }
  __syncthreads();
  const int na = act_n;
  const bool ok = (na <= ACT_PAD);

  unsigned ae[EPT];
  unsigned short r0[EPT], r1[EPT], r2[EPT];
#pragma unroll
  for (int e = 0; e < EPT; ++e) {
    unsigned v = act[tid + e * NTHR2];
    ae[e] = v;
    int k = (int)(v & 0xFFFFu);
    int c = (int)(v >> 16);
    const unsigned short* row = nbr + (size_t)k * K_NBR;
    r0[e] = (c > 0) ? row[0] : (unsigned short)0;
    r1[e] = (c > 1) ? row[1] : (unsigned short)0;
    r2[e] = (c > 2) ? row[2] : (unsigned short)0;
  }
  __syncthreads();

  if (ok) {
    for (int it = 0; it < 96; ++it) {
      int any = 0;
      int m0[EPT];
#pragma unroll
      for (int e = 0; e < EPT; ++e) m0[e] = (int)mask[r0[e]];  // batched
#pragma unroll
      for (int e = 0; e < EPT; ++e) {
        unsigned v = ae[e];
        int c = (int)(v >> 16);
        if (!c) continue;
        int k = (int)(v & 0xFFFFu);
        int kp = m0[e] ^ 1;
        if (c > 1) kp &= (int)mask[r1[e]] ^ 1;
        if (c > 2) kp &= (int)mask[r2[e]] ^ 1;
        if (c > 3) {   // ~0.2% of active points
          const unsigned short* row = nbr + (size_t)k * K_NBR;
          for (int t = 3; t < c; ++t) kp &= (int)mask[row[t]] ^ 1;
        }
        if (kp != (int)mask[k]) { mask[k] = (unsigned char)kp; any = 1; }
      }
      if (__syncthreads_count(any) == 0) break;
    }
  } else {
    // overflow fallback (statistically never): barriered global sweeps
    __shared__ int changed;
    for (int it = 0; it < 512; ++it) {
      if (tid == 0) changed = 0;
      __syncthreads();
      int any = 0;
      for (int k = tid; k < M_PTS; k += NTHR2) {
        int c = cnt[k]; if (c > K_NBR) c = K_NBR;
        if (!c) continue;
        int kp = 1;
        for (int t = 0; t < c; ++t) kp &= (int)mask[nbr[k * K_NBR + t]] ^ 1;
        if (kp != (int)mask[k]) { mask_[k] = (unsigned char)kp; any = 1; }
      }
      if (any) changed = 1;
      __syncthreads();
      if (!changed) break;
    }
  }
  __syncthreads();

  int ks = 0;
  for (int k = tid; k < M_PTS; k += NTHR2) {
    int m = (int)mask_[k];
    out[k] = m;
    ks += m;
  }
#pragma unroll
  for (int off = 32; off > 0; off >>= 1) ks += __shfl_down(ks, off, 64);
  if (lane64 == 0) atomicAdd(&total, ks);
  __syncthreads();
  if (tid == 0) out[out_size - 1] = total;
}

extern "C" void kernel_launch(void* const* d_in, const int* in_sizes, int n_in,
                              void* d_out, int out_size, void* d_ws, size_t ws_size,
                              hipStream_t stream) {
  const float* nodes = (const float*)d_in[0];
  const float* score = (const float*)d_in[1];
  int* out = (int*)d_out;

  char* ws = (char*)d_ws;
  float4* pts = (float4*)ws;
  int* cell_cnt = (int*)(ws + 262144);
  int* done = (int*)(ws + 324644);
  int* cnt = (int*)(ws + 327680);
  unsigned short* cell_list = (unsigned short*)(ws + 393216);
  unsigned short* nbr = (unsigned short*)(ws + 770048);

  build1b<<<1, 1024, 0, stream>>>(nodes, score, pts, cell_cnt, cell_list, done);
  scan_solve<<<NBLK2, NTHR2, 0, stream>>>(pts, cell_cnt, cell_list, cnt, nbr,
                                          done, out, out_size);
}

// Round 9
// 87.420 us; speedup vs baseline: 1.5995x; 1.0207x over previous
//
#include <hip/hip_runtime.h>

// Greedy NMS, M=16384 pts, radius 2.0, torch PairwiseDistance eps=1e-6.
// Output INT32: mask[16384] as 0/1, then count[1].
//
// Round 9: two dispatches, no in-kernel cross-block handoff.
//  K1 bin_scan (16 blocks x 1024): each block REDUNDANTLY bins all 16K points
//    into LDS ccnt + a PRIVATE global cell_list region (no races, same-XCD
//    reuse), then scans its own 1024 points against its own list. Emits
//    out[i]=1 for c==0 points and packed active entries (k,c,r0,r1,r2).
//  K2 solve2 (1 block): gathers active entries (~47KB coalesced), register-
//    stages rows, runs the proven r6 fixpoint sweeps, writes active outs +
//    count. Cross-XCD visibility via the kernel boundary (the cheap barrier).

#define M_PTS    16384
#define RADIUS   2.0f
#define EPS_D    1e-6f
#define GRID_N   25        // 4 m cells over 100 m scene
#define NCELLS   (GRID_N * GRID_N * GRID_N)
#define CELL_CAP 12
#define K_NBR    12
#define NBLK1    16
#define PPB      (M_PTS / NBLK1)      // 1024 points per K1 block
#define ACT_PAD  6144                 // E[active]~3932, sigma~55 -> 40 sigma
#define EPT      6                    // ACT_PAD / 1024

// ws layout (bytes):
//   [0,       393216) ushort nbr[16384*12]         (full rows, c>3 tail + fallback)
//   [393216,  393280) int    cnt_part[16]
//   [397312,  593920) uint   act_part[16][1024][3] (12B packed entries)
//   [1048576, ~7MB)   ushort cell_list[16][15625*12] private regions
#define LIST_STRIDE_E 187520   // elements (15625*12=187500, padded to 64B)
#define ACT_STRIDE_W  (1024 * 3)

__device__ __forceinline__ int cell_of(float v) {
  int c = (int)(v * 0.25f);
  return c < 0 ? 0 : (c > GRID_N - 1 ? GRID_N - 1 : c);
}

__device__ __forceinline__ bool edge_test(float xi, float yi, float zi, float si,
                                          float xj, float yj, float zj, float sj,
                                          int j, int i) {
  // j earlier in argsort(-score, stable) AND torch-dist <= radius (exact math)
  bool earlier = (sj > si) || ((sj == si) && (j < i));
  if (!earlier) return false;
  float ddx = __fadd_rn(__fsub_rn(xi, xj), EPS_D);
  float ddy = __fadd_rn(__fsub_rn(yi, yj), EPS_D);
  float ddz = __fadd_rn(__fsub_rn(zi, zj), EPS_D);
  float d2 = __fadd_rn(__fadd_rn(__fmul_rn(ddx, ddx), __fmul_rn(ddy, ddy)),
                       __fmul_rn(ddz, ddz));
  return !(__fsqrt_rn(d2) > RADIUS);
}

// ---- K1: private bin + scan own slice + compact active entries ----
__global__ __launch_bounds__(1024) void bin_scan(
    const float* __restrict__ nodes, const float* __restrict__ score,
    unsigned short* __restrict__ lists, unsigned int* __restrict__ act_part,
    int* __restrict__ cnt_part, unsigned short* __restrict__ nbr,
    int* __restrict__ out) {
  __shared__ int ccnt[NCELLS];   // 62.5 KB
  __shared__ int nact;
  const int tid = threadIdx.x;
  const int b   = blockIdx.x;
  unsigned short* mylist = lists + (size_t)b * LIST_STRIDE_E;

  for (int c = tid; c < NCELLS; c += 1024) ccnt[c] = 0;
  if (tid == 0) nact = 0;
  __syncthreads();

  // bin ALL points into the private list (order within cell nondeterministic;
  // downstream logic is set-invariant)
  for (int i = tid; i < M_PTS; i += 1024) {
    float x = nodes[3 * i + 0];
    float y = nodes[3 * i + 1];
    float z = nodes[3 * i + 2];
    int cid = (cell_of(x) * GRID_N + cell_of(y)) * GRID_N + cell_of(z);
    int pos = atomicAdd(&ccnt[cid], 1);
    if (pos < CELL_CAP) mylist[cid * CELL_CAP + pos] = (unsigned short)i;
  }
  __syncthreads();

  // scan own point (thread-per-point; ccnt reads are LDS, list reads same-XCD L2)
  const int i = b * PPB + tid;
  const float xi = nodes[3 * i + 0];
  const float yi = nodes[3 * i + 1];
  const float zi = nodes[3 * i + 2];
  const float si = score[i];
  const int cx = cell_of(xi), cy = cell_of(yi), cz = cell_of(zi);
  unsigned short row[3] = {0, 0, 0};
  int n = 0;
  for (int dx = -1; dx <= 1; ++dx) {
    int x = cx + dx; if (x < 0 || x >= GRID_N) continue;
    for (int dy = -1; dy <= 1; ++dy) {
      int y = cy + dy; if (y < 0 || y >= GRID_N) continue;
      for (int dz = -1; dz <= 1; ++dz) {
        int z = cz + dz; if (z < 0 || z >= GRID_N) continue;
        int cid = (x * GRID_N + y) * GRID_N + z;
        int m = ccnt[cid]; if (m > CELL_CAP) m = CELL_CAP;
        for (int s = 0; s < m; ++s) {
          int j = mylist[cid * CELL_CAP + s];
          float xj = nodes[3 * j + 0];
          float yj = nodes[3 * j + 1];
          float zj = nodes[3 * j + 2];
          float sj = score[j];
          if (edge_test(xi, yi, zi, si, xj, yj, zj, sj, j, i)) {
            if (n < 3)     row[n] = (unsigned short)j;
            if (n < K_NBR) nbr[i * K_NBR + n] = (unsigned short)j;
            ++n;
          }
        }
      }
    }
  }
  int c = n > K_NBR ? K_NBR : n;
  if (c == 0) out[i] = 1;   // unsuppressible: kept forever

  // ballot-compact active entries into this block's private region
  unsigned long long bal = __ballot(c > 0);
  const int lane = tid & 63;
  int wcnt = __popcll(bal);
  int wbase = 0;
  if (lane == 0 && wcnt) wbase = atomicAdd(&nact, wcnt);
  wbase = __shfl(wbase, 0, 64);
  if (c > 0) {
    int pos = wbase + __popcll(bal & ((1ull << lane) - 1ull));
    unsigned int* e = act_part + (size_t)b * ACT_STRIDE_W + (size_t)pos * 3;
    e[0] = (unsigned)i | ((unsigned)c << 16);
    e[1] = (unsigned)row[0] | ((unsigned)row[1] << 16);
    e[2] = (unsigned)row[2];
  }
  __syncthreads();
  if (tid == 0) cnt_part[b] = nact;
}

// ---- K2: single block, gather + register-staged fixpoint solve ----
__global__ __launch_bounds__(1024) void solve2(
    const unsigned int* __restrict__ act_part, const int* __restrict__ cnt_part,
    const unsigned short* __restrict__ nbr, int* __restrict__ out, int out_size) {
  __shared__ unsigned char mask_[M_PTS];   // 16 KB
  __shared__ unsigned int a0[ACT_PAD];     // k | c<<16     } 72 KB
  __shared__ unsigned int a1[ACT_PAD];     // r0 | r1<<16   }
  __shared__ unsigned int a2[ACT_PAD];     // r2            }
  __shared__ int offs[NBLK1 + 1];
  __shared__ int cpart[NBLK1];
  __shared__ int total;
  volatile unsigned char* mask = mask_;

  const int tid = threadIdx.x;
  const int lane = tid & 63;

  for (int k = tid; k < M_PTS; k += 1024) mask_[k] = 1;
  if (tid < NBLK1) cpart[tid] = cnt_part[tid];   // parallel loads
  if (tid == 0) total = 0;
  __syncthreads();
  if (tid == 0) {
    int acc = 0;
    for (int bb = 0; bb < NBLK1; ++bb) { offs[bb] = acc; acc += cpart[bb]; }
    offs[NBLK1] = acc;
  }
  __syncthreads();
  const int na = offs[NBLK1];
  const bool ok = (na <= ACT_PAD);

  if (ok) {
    for (int bb = 0; bb < NBLK1; ++bb) {
      int base = offs[bb], nb = offs[bb + 1] - base;
      const unsigned int* src = act_part + (size_t)bb * ACT_STRIDE_W;
      for (int e = tid; e < nb; e += 1024) {
        a0[base + e] = src[e * 3 + 0];
        a1[base + e] = src[e * 3 + 1];
        a2[base + e] = src[e * 3 + 2];
      }
    }
    for (int e = na + tid; e < ACT_PAD; e += 1024) { a0[e] = 0; a1[e] = 0; a2[e] = 0; }
  }
  __syncthreads();

  if (ok) {
    // register staging (c=0 sentinels in the tail are skipped in sweeps)
    unsigned ae[EPT];
    unsigned short r0[EPT], r1[EPT], r2[EPT];
#pragma unroll
    for (int e = 0; e < EPT; ++e) {
      int idx = tid + e * 1024;
      ae[e] = a0[idx];
      unsigned w1 = a1[idx], w2 = a2[idx];
      r0[e] = (unsigned short)(w1 & 0xFFFFu);
      r1[e] = (unsigned short)(w1 >> 16);
      r2[e] = (unsigned short)(w2 & 0xFFFFu);
    }
    __syncthreads();

    for (int it = 0; it < 96; ++it) {
      int any = 0;
      int m0[EPT];
#pragma unroll
      for (int e = 0; e < EPT; ++e) m0[e] = (int)mask[r0[e]];  // batched reads
#pragma unroll
      for (int e = 0; e < EPT; ++e) {
        unsigned v = ae[e];
        int c = (int)(v >> 16);
        if (!c) continue;
        int k = (int)(v & 0xFFFFu);
        int kp = m0[e] ^ 1;
        if (c > 1) kp &= (int)mask[r1[e]] ^ 1;
        if (c > 2) kp &= (int)mask[r2[e]] ^ 1;
        if (c > 3) {   // ~0.2% of active points
          const unsigned short* rowp = nbr + (size_t)k * K_NBR;
          for (int t = 3; t < c; ++t) kp &= (int)mask[rowp[t]] ^ 1;
        }
        if (kp != (int)mask[k]) { mask[k] = (unsigned char)kp; any = 1; }
      }
      if (__syncthreads_count(any) == 0) break;
    }

    // epilogue: write ONLY active outputs; inactive were written by K1
    int ks = 0;
    for (int e = tid; e < na; e += 1024) {
      int k = (int)(a0[e] & 0xFFFFu);
      int m = (int)mask_[k];
      out[k] = m;
      ks += m;
    }
#pragma unroll
    for (int off = 32; off > 0; off >>= 1) ks += __shfl_down(ks, off, 64);
    if (lane == 0) atomicAdd(&total, ks);
    __syncthreads();
    if (tid == 0) out[out_size - 1] = (M_PTS - na) + total;
  } else {
    // overflow fallback (statistically never): barriered sweeps via act_part
    __shared__ int changed;
    for (int it = 0; it < 512; ++it) {
      if (tid == 0) changed = 0;
      __syncthreads();
      int any = 0;
      for (int bb = 0; bb < NBLK1; ++bb) {
        int nb = cpart[bb];
        const unsigned int* src = act_part + (size_t)bb * ACT_STRIDE_W;
        for (int e = tid; e < nb; e += 1024) {
          unsigned v = src[e * 3 + 0];
          int k = (int)(v & 0xFFFFu);
          int c = (int)(v >> 16);
          int kp = 1;
          const unsigned short* rowp = nbr + (size_t)k * K_NBR;
          for (int t = 0; t < c; ++t) kp &= (int)mask[rowp[t]] ^ 1;
          if (kp != (int)mask[k]) { mask_[k] = (unsigned char)kp; any = 1; }
        }
      }
      if (any) changed = 1;
      __syncthreads();
      if (!changed) break;
    }
    __syncthreads();
    int ks = 0;
    for (int bb = 0; bb < NBLK1; ++bb) {
      int nb = cpart[bb];
      const unsigned int* src = act_part + (size_t)bb * ACT_STRIDE_W;
      for (int e = tid; e < nb; e += 1024) {
        int k = (int)(src[e * 3] & 0xFFFFu);
        int m = (int)mask_[k];
        out[k] = m;
        ks += m;
      }
    }
#pragma unroll
    for (int off = 32; off > 0; off >>= 1) ks += __shfl_down(ks, off, 64);
    if (lane == 0) atomicAdd(&total, ks);
    __syncthreads();
    if (tid == 0) out[out_size - 1] = (M_PTS - na) + total;
  }
}

extern "C" void kernel_launch(void* const* d_in, const int* in_sizes, int n_in,
                              void* d_out, int out_size, void* d_ws, size_t ws_size,
                              hipStream_t stream) {
  const float* nodes = (const float*)d_in[0];
  const float* score = (const float*)d_in[1];
  int* out = (int*)d_out;

  char* ws = (char*)d_ws;
  unsigned short* nbr = (unsigned short*)ws;                 // 393216 B
  int* cnt_part = (int*)(ws + 393216);                       // 64 B
  unsigned int* act_part = (unsigned int*)(ws + 397312);     // 196608 B
  unsigned short* lists = (unsigned short*)(ws + 1048576);   // 16 private regions

  bin_scan<<<NBLK1, 1024, 0, stream>>>(nodes, score, lists, act_part,
                                       cnt_part, nbr, out);
  solve2<<<1, 1024, 0, stream>>>(act_part, cnt_part, nbr, out, out_size);
}

// Round 10
// 51.311 us; speedup vs baseline: 2.7252x; 1.7037x over previous
//
#include <hip/hip_runtime.h>

// Greedy NMS, M=16384 pts, radius 2.0, torch PairwiseDistance eps=1e-6.
// Output INT32: mask[16384] as 0/1, then count[1].
//
// Round 10: 3 nodes.
//  K1 bin1b (1x1024): LDS cell table (zero->bin->flush, no global pre-zero),
//     writes pts float4 + cell_list + clamped cell_cnt.
//  K2 wscan (2048x256): ONE task per wave (r8 failed with 4): 2 points/wave,
//     one candidate cell per lane, shfl-scan packing, no atomics, no zeroing.
//  K3 solve (1x1024): r6's proven register-staged fixpoint + output.

#define M_PTS    16384
#define RADIUS   2.0f
#define EPS_D    1e-6f
#define GRID_N   25        // 4 m cells over 100 m scene
#define NCELLS   (GRID_N * GRID_N * GRID_N)
#define CELL_CAP 12
#define K_NBR    12
#define EPT      5
#define ACT_PAD  (EPT * 1024)   // 5120; E[active]~3932, sigma~55

// ws layout (bytes):
//   [0,       262144) float4 pts[16384]
//   [262144,  324644) int    cell_cnt[15625]
//   [327680,  393216) int    cnt[16384]
//   [393216,  768216) ushort cell_list[15625*12]
//   [770048, 1163264) ushort nbr[16384*12]

__device__ __forceinline__ int cell_of(float v) {
  int c = (int)(v * 0.25f);
  return c < 0 ? 0 : (c > GRID_N - 1 ? GRID_N - 1 : c);
}

__device__ __forceinline__ bool edge_test(float4 pi, float4 pj, int j, int i) {
  // j earlier in argsort(-score, stable) AND torch-dist <= radius (exact math)
  bool earlier = (pj.w > pi.w) || ((pj.w == pi.w) && (j < i));
  if (!earlier) return false;
  float ddx = __fadd_rn(__fsub_rn(pi.x, pj.x), EPS_D);
  float ddy = __fadd_rn(__fsub_rn(pi.y, pj.y), EPS_D);
  float ddz = __fadd_rn(__fsub_rn(pi.z, pj.z), EPS_D);
  float d2 = __fadd_rn(__fadd_rn(__fmul_rn(ddx, ddx), __fmul_rn(ddy, ddy)),
                       __fmul_rn(ddz, ddz));
  return !(__fsqrt_rn(d2) > RADIUS);
}

// ---- K1: single block. LDS cell table: zero -> bin -> flush. ----
__global__ __launch_bounds__(1024) void bin1b(
    const float* __restrict__ nodes, const float* __restrict__ score,
    float4* __restrict__ pts, int* __restrict__ cell_cnt,
    unsigned short* __restrict__ cell_list) {
  __shared__ int ccnt[NCELLS];   // 62.5 KB
  const int tid = threadIdx.x;
  for (int c = tid; c < NCELLS; c += 1024) ccnt[c] = 0;
  __syncthreads();
  for (int i = tid; i < M_PTS; i += 1024) {
    float4 p;
    p.x = nodes[3 * i + 0];
    p.y = nodes[3 * i + 1];
    p.z = nodes[3 * i + 2];
    p.w = score[i];
    pts[i] = p;
    int cid = (cell_of(p.x) * GRID_N + cell_of(p.y)) * GRID_N + cell_of(p.z);
    int pos = atomicAdd(&ccnt[cid], 1);
    if (pos < CELL_CAP) cell_list[cid * CELL_CAP + pos] = (unsigned short)i;
  }
  __syncthreads();
  for (int c = tid; c < NCELLS; c += 1024) {
    int v = ccnt[c];
    cell_cnt[c] = v > CELL_CAP ? CELL_CAP : v;
  }
}

// ---- K2: 2 points per wave, one cell per lane, ONE task per wave. ----
// 2048 blocks x 256 = 8192 waves = 16384 points. No atomics, no pre-zero.
__global__ __launch_bounds__(256) void wscan(
    const float4* __restrict__ pts, const int* __restrict__ cell_cnt,
    const unsigned short* __restrict__ cell_list,
    int* __restrict__ cnt, unsigned short* __restrict__ nbr) {
  const int tid  = threadIdx.x;
  const int lane = tid & 63;
  const int d    = lane & 31;     // cell slot: 0..26 active
  const int half = lane >> 5;     // which of the wave's 2 points
  const int gwave = (blockIdx.x * 256 + tid) >> 6;   // 0..8191
  const int i = gwave * 2 + half;

  const float4 pi = pts[i];       // broadcast load per 32-half
  int n = 0, cid = 0, m = 0, firstj = 0;
  if (d < 27) {
    int cx = cell_of(pi.x) + d / 9 - 1;
    int cy = cell_of(pi.y) + (d / 3) % 3 - 1;
    int cz = cell_of(pi.z) + d % 3 - 1;
    if (cx >= 0 && cx < GRID_N && cy >= 0 && cy < GRID_N &&
        cz >= 0 && cz < GRID_N) {
      cid = (cx * GRID_N + cy) * GRID_N + cz;
      m = cell_cnt[cid];          // already clamped <= CELL_CAP
      for (int s = 0; s < m; ++s) {
        int j = cell_list[cid * CELL_CAP + s];
        if (edge_test(pi, pts[j], j, i)) { if (!n) firstj = j; ++n; }
      }
    }
  }
  // segmented inclusive scan over the 32-lane half -> packing offsets
  int x = n;
#pragma unroll
  for (int off = 1; off < 32; off <<= 1) {
    int y = __shfl_up(x, off, 32);
    if (d >= off) x += y;
  }
  int excl = x - n;
  int tot = __shfl(x, 31, 32);
  if (n == 1) {                   // common case: direct write, no rescan
    if (excl < K_NBR) nbr[i * K_NBR + excl] = (unsigned short)firstj;
  } else if (n > 1) {             // rare: rescan L1-hot cell list
    int pos = excl;
    for (int s = 0; s < m && pos < K_NBR; ++s) {
      int j = cell_list[cid * CELL_CAP + s];
      if (edge_test(pi, pts[j], j, i)) {
        nbr[i * K_NBR + pos] = (unsigned short)j;
        ++pos;
      }
    }
  }
  if (d == 0) cnt[i] = tot > K_NBR ? K_NBR : tot;
}

// ---- K3: single block, register-staged fixpoint solve (r6, proven) ----
__global__ __launch_bounds__(1024) void solve_kernel(
    const int* __restrict__ cnt, const unsigned short* __restrict__ nbr,
    int* __restrict__ out, int out_size) {
  __shared__ unsigned char mask_[M_PTS];   // 16 KB
  __shared__ unsigned int act[ACT_PAD];    // 20 KB: k | (c<<16)
  __shared__ int act_n, total;
  volatile unsigned char* mask = mask_;

  const int tid = threadIdx.x;
  const int lane = tid & 63;
  if (tid == 0) { act_n = 0; total = 0; }
  for (int a = tid; a < ACT_PAD; a += 1024) act[a] = 0u;  // c=0 sentinels
  __syncthreads();

  // active-list build: ballot compaction, one atomic per wave per step
  for (int k = tid; k < M_PTS; k += 1024) {   // exactly 16 full steps
    mask_[k] = 1;
    int c = cnt[k];
    if (c > K_NBR) c = K_NBR;
    unsigned long long b = __ballot(c > 0);
    int wcnt = __popcll(b);
    int wbase = 0;
    if (lane == 0 && wcnt) wbase = atomicAdd(&act_n, wcnt);
    wbase = __shfl(wbase, 0, 64);
    if (c > 0) {
      int pos = wbase + __popcll(b & ((1ull << lane) - 1ull));
      if (pos < ACT_PAD) act[pos] = (unsigned)k | ((unsigned)c << 16);
    }
  }
  __syncthreads();
  const int na = act_n;
  const bool ok = (na <= ACT_PAD);

  // stage this thread's 5 entries: act word + neighbor rows 0..2 in regs
  unsigned ae[EPT];
  unsigned short r0[EPT], r1[EPT], r2[EPT];
#pragma unroll
  for (int e = 0; e < EPT; ++e) {
    unsigned v = act[tid + e * 1024];
    ae[e] = v;
    int k = (int)(v & 0xFFFFu);
    int c = (int)(v >> 16);
    const unsigned short* row = nbr + (size_t)k * K_NBR;
    r0[e] = (c > 0) ? row[0] : (unsigned short)0;
    r1[e] = (c > 1) ? row[1] : (unsigned short)0;
    r2[e] = (c > 2) ? row[2] : (unsigned short)0;
  }
  __syncthreads();

  if (ok) {
    for (int it = 0; it < 96; ++it) {
      int any = 0;
      int m0[EPT];
#pragma unroll
      for (int e = 0; e < EPT; ++e) m0[e] = (int)mask[r0[e]];  // batched
#pragma unroll
      for (int e = 0; e < EPT; ++e) {
        unsigned v = ae[e];
        int c = (int)(v >> 16);
        if (!c) continue;
        int k = (int)(v & 0xFFFFu);
        int kp = m0[e] ^ 1;
        if (c > 1) kp &= (int)mask[r1[e]] ^ 1;
        if (c > 2) kp &= (int)mask[r2[e]] ^ 1;
        if (c > 3) {   // ~0.2% of active points
          const unsigned short* row = nbr + (size_t)k * K_NBR;
          for (int t = 3; t < c; ++t) kp &= (int)mask[row[t]] ^ 1;
        }
        if (kp != (int)mask[k]) { mask[k] = (unsigned char)kp; any = 1; }
      }
      if (__syncthreads_count(any) == 0) break;
    }
  } else {
    // overflow fallback (statistically never): barriered global sweeps
    __shared__ int changed;
    for (int it = 0; it < 512; ++it) {
      if (tid == 0) changed = 0;
      __syncthreads();
      int any = 0;
      for (int k = tid; k < M_PTS; k += 1024) {
        int c = cnt[k]; if (c > K_NBR) c = K_NBR;
        if (!c) continue;
        int kp = 1;
        for (int t = 0; t < c; ++t) kp &= (int)mask[nbr[k * K_NBR + t]] ^ 1;
        if (kp != (int)mask[k]) { mask_[k] = (unsigned char)kp; any = 1; }
      }
      if (any) changed = 1;
      __syncthreads();
      if (!changed) break;
    }
  }
  __syncthreads();

  int ks = 0;
  for (int k = tid; k < M_PTS; k += 1024) {
    int m = (int)mask_[k];
    out[k] = m;
    ks += m;
  }
#pragma unroll
  for (int off = 32; off > 0; off >>= 1) ks += __shfl_down(ks, off, 64);
  if (lane == 0) atomicAdd(&total, ks);
  __syncthreads();
  if (tid == 0) out[out_size - 1] = total;
}

extern "C" void kernel_launch(void* const* d_in, const int* in_sizes, int n_in,
                              void* d_out, int out_size, void* d_ws, size_t ws_size,
                              hipStream_t stream) {
  const float* nodes = (const float*)d_in[0];
  const float* score = (const float*)d_in[1];
  int* out = (int*)d_out;

  char* ws = (char*)d_ws;
  float4* pts = (float4*)ws;
  int* cell_cnt = (int*)(ws + 262144);
  int* cnt = (int*)(ws + 327680);
  unsigned short* cell_list = (unsigned short*)(ws + 393216);
  unsigned short* nbr = (unsigned short*)(ws + 770048);

  bin1b<<<1, 1024, 0, stream>>>(nodes, score, pts, cell_cnt, cell_list);
  wscan<<<2048, 256, 0, stream>>>(pts, cell_cnt, cell_list, cnt, nbr);
  solve_kernel<<<1, 1024, 0, stream>>>(cnt, nbr, out, out_size);
}

// Round 11
// 42.701 us; speedup vs baseline: 3.2747x; 1.2017x over previous
//
#include <hip/hip_runtime.h>

// Greedy NMS, M=16384 pts, radius 2.0, torch PairwiseDistance eps=1e-6.
// Output INT32: mask[16384] as 0/1, then count[1].
//
// Round 11: 3 nodes, all multi-block, no zero-kernel, no global atomics in build.
//  K1 bin25 (25 blocks x 1024): block b owns the 625 cells with cx==b. Streams
//     all x-coords, bins its own points via private LDS table, writes pts for
//     owned points, flushes contiguous cell_cnt/cell_list slices. No races.
//  K2 wscan (2048x256, proven r10): 2 points/wave, one cell/lane, shfl-scan
//     packing, no atomics, no cnt zeroing.
//  K3 solve (1x1024, proven r6): register-staged fixpoint + output.

#define M_PTS    16384
#define RADIUS   2.0f
#define EPS_D    1e-6f
#define GRID_N   25        // 4 m cells over 100 m scene
#define NCELLS   (GRID_N * GRID_N * GRID_N)
#define CELL_CAP 12
#define K_NBR    12
#define EPT      5
#define ACT_PAD  (EPT * 1024)   // 5120; E[active]~3932, sigma~55
#define CELLS_PB (GRID_N * GRID_N)        // 625 cells per bin-block
#define LIST_PB  (CELLS_PB * CELL_CAP)    // 7500 entries per bin-block

// ws layout (bytes):
//   [0,       262144) float4 pts[16384]
//   [262144,  324644) int    cell_cnt[15625]
//   [327680,  393216) int    cnt[16384]
//   [393216,  768216) ushort cell_list[15625*12]
//   [770048, 1163264) ushort nbr[16384*12]

__device__ __forceinline__ int cell_of(float v) {
  int c = (int)(v * 0.25f);
  return c < 0 ? 0 : (c > GRID_N - 1 ? GRID_N - 1 : c);
}

__device__ __forceinline__ bool edge_test(float4 pi, float4 pj, int j, int i) {
  // j earlier in argsort(-score, stable) AND torch-dist <= radius (exact math)
  bool earlier = (pj.w > pi.w) || ((pj.w == pi.w) && (j < i));
  if (!earlier) return false;
  float ddx = __fadd_rn(__fsub_rn(pi.x, pj.x), EPS_D);
  float ddy = __fadd_rn(__fsub_rn(pi.y, pj.y), EPS_D);
  float ddz = __fadd_rn(__fsub_rn(pi.z, pj.z), EPS_D);
  float d2 = __fadd_rn(__fadd_rn(__fmul_rn(ddx, ddx), __fmul_rn(ddy, ddy)),
                       __fmul_rn(ddz, ddz));
  return !(__fsqrt_rn(d2) > RADIUS);
}

// ---- K1: 25 blocks; block b owns all cells with cx==b (625 cells). ----
__global__ __launch_bounds__(1024) void bin25(
    const float* __restrict__ nodes, const float* __restrict__ score,
    float4* __restrict__ pts, int* __restrict__ cell_cnt,
    unsigned short* __restrict__ cell_list) {
  __shared__ int ccnt[CELLS_PB];              // 2.5 KB
  __shared__ unsigned short clist[LIST_PB];   // 15 KB
  const int tid = threadIdx.x;
  const int b   = blockIdx.x;
  if (tid < CELLS_PB) ccnt[tid] = 0;
  __syncthreads();

  for (int i = tid; i < M_PTS; i += 1024) {   // 16 full strided steps
    float x = nodes[3 * i + 0];
    if (cell_of(x) != b) continue;            // not ours
    float y = nodes[3 * i + 1];
    float z = nodes[3 * i + 2];
    float s = score[i];
    pts[i] = make_float4(x, y, z, s);         // exactly one owner per point
    int lc = cell_of(y) * GRID_N + cell_of(z);
    int pos = atomicAdd(&ccnt[lc], 1);        // LDS atomic, 625 addresses
    if (pos < CELL_CAP) clist[lc * CELL_CAP + pos] = (unsigned short)i;
  }
  __syncthreads();

  if (tid < CELLS_PB) {
    int v = ccnt[tid];
    cell_cnt[b * CELLS_PB + tid] = v > CELL_CAP ? CELL_CAP : v;
  }
  // flush full slice (entries beyond count are never read; bounded by cell_cnt)
  for (int e = tid; e < LIST_PB; e += 1024)
    cell_list[b * LIST_PB + e] = clist[e];
}

// ---- K2: 2 points per wave, one cell per lane, one task per wave. ----
// 2048 blocks x 256 = 8192 waves = 16384 points. No atomics, no pre-zero.
__global__ __launch_bounds__(256) void wscan(
    const float4* __restrict__ pts, const int* __restrict__ cell_cnt,
    const unsigned short* __restrict__ cell_list,
    int* __restrict__ cnt, unsigned short* __restrict__ nbr) {
  const int tid  = threadIdx.x;
  const int lane = tid & 63;
  const int d    = lane & 31;     // cell slot: 0..26 active
  const int half = lane >> 5;     // which of the wave's 2 points
  const int gwave = (blockIdx.x * 256 + tid) >> 6;   // 0..8191
  const int i = gwave * 2 + half;

  const float4 pi = pts[i];
  int n = 0, cid = 0, m = 0, firstj = 0;
  if (d < 27) {
    int cx = cell_of(pi.x) + d / 9 - 1;
    int cy = cell_of(pi.y) + (d / 3) % 3 - 1;
    int cz = cell_of(pi.z) + d % 3 - 1;
    if (cx >= 0 && cx < GRID_N && cy >= 0 && cy < GRID_N &&
        cz >= 0 && cz < GRID_N) {
      cid = (cx * GRID_N + cy) * GRID_N + cz;
      m = cell_cnt[cid];          // already clamped <= CELL_CAP
      for (int s = 0; s < m; ++s) {
        int j = cell_list[cid * CELL_CAP + s];
        if (edge_test(pi, pts[j], j, i)) { if (!n) firstj = j; ++n; }
      }
    }
  }
  // segmented inclusive scan over the 32-lane half -> packing offsets
  int x = n;
#pragma unroll
  for (int off = 1; off < 32; off <<= 1) {
    int y = __shfl_up(x, off, 32);
    if (d >= off) x += y;
  }
  int excl = x - n;
  int tot = __shfl(x, 31, 32);
  if (n == 1) {                   // common case: direct write, no rescan
    if (excl < K_NBR) nbr[i * K_NBR + excl] = (unsigned short)firstj;
  } else if (n > 1) {             // rare: rescan L1-hot cell list
    int pos = excl;
    for (int s = 0; s < m && pos < K_NBR; ++s) {
      int j = cell_list[cid * CELL_CAP + s];
      if (edge_test(pi, pts[j], j, i)) {
        nbr[i * K_NBR + pos] = (unsigned short)j;
        ++pos;
      }
    }
  }
  if (d == 0) cnt[i] = tot > K_NBR ? K_NBR : tot;
}

// ---- K3: single block, register-staged fixpoint solve (r6, proven) ----
__global__ __launch_bounds__(1024) void solve_kernel(
    const int* __restrict__ cnt, const unsigned short* __restrict__ nbr,
    int* __restrict__ out, int out_size) {
  __shared__ unsigned char mask_[M_PTS];   // 16 KB
  __shared__ unsigned int act[ACT_PAD];    // 20 KB: k | (c<<16)
  __shared__ int act_n, total;
  volatile unsigned char* mask = mask_;

  const int tid = threadIdx.x;
  const int lane = tid & 63;
  if (tid == 0) { act_n = 0; total = 0; }
  for (int a = tid; a < ACT_PAD; a += 1024) act[a] = 0u;  // c=0 sentinels
  __syncthreads();

  // active-list build: ballot compaction, one atomic per wave per step
  for (int k = tid; k < M_PTS; k += 1024) {   // exactly 16 full steps
    mask_[k] = 1;
    int c = cnt[k];
    if (c > K_NBR) c = K_NBR;
    unsigned long long b = __ballot(c > 0);
    int wcnt = __popcll(b);
    int wbase = 0;
    if (lane == 0 && wcnt) wbase = atomicAdd(&act_n, wcnt);
    wbase = __shfl(wbase, 0, 64);
    if (c > 0) {
      int pos = wbase + __popcll(b & ((1ull << lane) - 1ull));
      if (pos < ACT_PAD) act[pos] = (unsigned)k | ((unsigned)c << 16);
    }
  }
  __syncthreads();
  const int na = act_n;
  const bool ok = (na <= ACT_PAD);

  // stage this thread's 5 entries: act word + neighbor rows 0..2 in regs
  unsigned ae[EPT];
  unsigned short r0[EPT], r1[EPT], r2[EPT];
#pragma unroll
  for (int e = 0; e < EPT; ++e) {
    unsigned v = act[tid + e * 1024];
    ae[e] = v;
    int k = (int)(v & 0xFFFFu);
    int c = (int)(v >> 16);
    const unsigned short* row = nbr + (size_t)k * K_NBR;
    r0[e] = (c > 0) ? row[0] : (unsigned short)0;
    r1[e] = (c > 1) ? row[1] : (unsigned short)0;
    r2[e] = (c > 2) ? row[2] : (unsigned short)0;
  }
  __syncthreads();

  if (ok) {
    for (int it = 0; it < 96; ++it) {
      int any = 0;
      int m0[EPT];
#pragma unroll
      for (int e = 0; e < EPT; ++e) m0[e] = (int)mask[r0[e]];  // batched
#pragma unroll
      for (int e = 0; e < EPT; ++e) {
        unsigned v = ae[e];
        int c = (int)(v >> 16);
        if (!c) continue;
        int k = (int)(v & 0xFFFFu);
        int kp = m0[e] ^ 1;
        if (c > 1) kp &= (int)mask[r1[e]] ^ 1;
        if (c > 2) kp &= (int)mask[r2[e]] ^ 1;
        if (c > 3) {   // ~0.2% of active points
          const unsigned short* row = nbr + (size_t)k * K_NBR;
          for (int t = 3; t < c; ++t) kp &= (int)mask[row[t]] ^ 1;
        }
        if (kp != (int)mask[k]) { mask[k] = (unsigned char)kp; any = 1; }
      }
      if (__syncthreads_count(any) == 0) break;
    }
  } else {
    // overflow fallback (statistically never): barriered global sweeps
    __shared__ int changed;
    for (int it = 0; it < 512; ++it) {
      if (tid == 0) changed = 0;
      __syncthreads();
      int any = 0;
      for (int k = tid; k < M_PTS; k += 1024) {
        int c = cnt[k]; if (c > K_NBR) c = K_NBR;
        if (!c) continue;
        int kp = 1;
        for (int t = 0; t < c; ++t) kp &= (int)mask[nbr[k * K_NBR + t]] ^ 1;
        if (kp != (int)mask[k]) { mask_[k] = (unsigned char)kp; any = 1; }
      }
      if (any) changed = 1;
      __syncthreads();
      if (!changed) break;
    }
  }
  __syncthreads();

  int ks = 0;
  for (int k = tid; k < M_PTS; k += 1024) {
    int m = (int)mask_[k];
    out[k] = m;
    ks += m;
  }
#pragma unroll
  for (int off = 32; off > 0; off >>= 1) ks += __shfl_down(ks, off, 64);
  if (lane == 0) atomicAdd(&total, ks);
  __syncthreads();
  if (tid == 0) out[out_size - 1] = total;
}

extern "C" void kernel_launch(void* const* d_in, const int* in_sizes, int n_in,
                              void* d_out, int out_size, void* d_ws, size_t ws_size,
                              hipStream_t stream) {
  const float* nodes = (const float*)d_in[0];
  const float* score = (const float*)d_in[1];
  int* out = (int*)d_out;

  char* ws = (char*)d_ws;
  float4* pts = (float4*)ws;
  int* cell_cnt = (int*)(ws + 262144);
  int* cnt = (int*)(ws + 327680);
  unsigned short* cell_list = (unsigned short*)(ws + 393216);
  unsigned short* nbr = (unsigned short*)(ws + 770048);

  bin25<<<GRID_N, 1024, 0, stream>>>(nodes, score, pts, cell_cnt, cell_list);
  wscan<<<2048, 256, 0, stream>>>(pts, cell_cnt, cell_list, cnt, nbr);
  solve_kernel<<<1, 1024, 0, stream>>>(cnt, nbr, out, out_size);
}